// Round 1
// baseline (416.536 us; speedup 1.0000x reference)
//
#include <hip/hip_runtime.h>
#include <hip/hip_bf16.h>
#include <stdint.h>

#define NN   100000
#define NE   1600000
#define KIN  256
#define FOUT 128

typedef __attribute__((ext_vector_type(8))) short short8;
typedef __attribute__((ext_vector_type(4))) float f32x4;
typedef __attribute__((ext_vector_type(2))) float f32x2;

static __device__ __forceinline__ unsigned short f2bf(float f) {
  unsigned int u = __float_as_uint(f);
  u += 0x7fffu + ((u >> 16) & 1u);   // round-to-nearest-even (inputs finite)
  return (unsigned short)(u >> 16);
}

// ---------------------------------------------------------------------------
// 1) x (fp32, [NN][256]) -> xb (bf16). 25.6M elems, float4 -> uint2 (4 bf16).
__global__ __launch_bounds__(256) void convert_x(const float* __restrict__ x,
                                                 unsigned short* __restrict__ xb) {
  int idx = blockIdx.x * 256 + threadIdx.x;          // float4 index, exact grid
  float4 v = ((const float4*)x)[idx];
  uint2 p;
  p.x = (unsigned)f2bf(v.x) | ((unsigned)f2bf(v.y) << 16);
  p.y = (unsigned)f2bf(v.z) | ((unsigned)f2bf(v.w) << 16);
  *(uint2*)(xb + (size_t)idx * 4) = p;
}

// ---------------------------------------------------------------------------
// 2) W[k][n] (fp32) -> wt[which][n][k] (bf16, transposed so B-fragments are
//    8 contiguous bf16 = one 16B load). grid (128, 2), block 256.
__global__ void convert_w(const float* __restrict__ W0, const float* __restrict__ W1,
                          unsigned short* __restrict__ wt) {
  int n = blockIdx.x;          // 0..127
  int k = threadIdx.x;         // 0..255
  int which = blockIdx.y;
  const float* W = which ? W1 : W0;
  wt[(size_t)which * (FOUT * KIN) + n * KIN + k] = f2bf(W[k * FOUT + n]);
}

// ---------------------------------------------------------------------------
// 3) rows sorted -> CSR row_ptr via lower_bound. grid (391, 2), block 256.
__global__ __launch_bounds__(256) void build_rowptr(const int* __restrict__ rows0,
                                                    const int* __restrict__ rows1,
                                                    int* __restrict__ rp0,
                                                    int* __restrict__ rp1) {
  int r = blockIdx.x * 256 + threadIdx.x;
  if (r > NN) return;
  const int* rows = blockIdx.y ? rows1 : rows0;
  int* rp = blockIdx.y ? rp1 : rp0;
  int lo = 0, hi = NE;
  while (lo < hi) {
    int mid = (lo + hi) >> 1;
    if (rows[mid] < r) lo = mid + 1; else hi = mid;
  }
  rp[r] = lo;
}

// ---------------------------------------------------------------------------
// 4) GEMM h[which] = bf16( x @ W[which] ).  Direct-global MFMA (no LDS):
//    block = 4 waves, block tile 64 rows x 128 cols, wave tile 32x64,
//    16x16x32 bf16 MFMA, K=256 in 8 steps. Working set/block: x 32KB + wt 64KB
//    rides L1/L2 (wt is hot in L2: 128KB total).
__global__ __launch_bounds__(256) void gemm_mfma(const unsigned short* __restrict__ xb,
                                                 const unsigned short* __restrict__ wt,
                                                 unsigned short* __restrict__ h) {
  const int tid  = threadIdx.x;
  const int lane = tid & 63;
  const int wv   = tid >> 6;
  const int which = blockIdx.y;
  const unsigned short* w = wt + (size_t)which * (FOUT * KIN);
  unsigned short* hh = h + (size_t)which * NN * FOUT;

  const int rowbase = blockIdx.x * 64 + (wv >> 1) * 32;  // wave's 32-row strip
  const int colbase = (wv & 1) * 64;                     // wave's 64-col strip
  const int m    = lane & 15;
  const int quad = lane >> 4;

  int r0 = rowbase + m;
  int r1 = rowbase + 16 + m;
  int r0c = r0 < NN ? r0 : NN - 1;   // clamp loads; stores masked in epilogue
  int r1c = r1 < NN ? r1 : NN - 1;

  const unsigned short* ap0 = xb + (size_t)r0c * KIN + quad * 8;
  const unsigned short* ap1 = xb + (size_t)r1c * KIN + quad * 8;
  const unsigned short* bp0 = w + (size_t)(colbase + 0  + m) * KIN + quad * 8;
  const unsigned short* bp1 = w + (size_t)(colbase + 16 + m) * KIN + quad * 8;
  const unsigned short* bp2 = w + (size_t)(colbase + 32 + m) * KIN + quad * 8;
  const unsigned short* bp3 = w + (size_t)(colbase + 48 + m) * KIN + quad * 8;

  f32x4 acc[2][4];
#pragma unroll
  for (int i = 0; i < 2; ++i)
#pragma unroll
    for (int j = 0; j < 4; ++j)
      acc[i][j] = (f32x4){0.f, 0.f, 0.f, 0.f};

#pragma unroll
  for (int ki = 0; ki < 8; ++ki) {
    const int ko = ki * 32;   // frag covers k = ko + quad*8 .. +7
    short8 a0 = *(const short8*)(ap0 + ko);
    short8 a1 = *(const short8*)(ap1 + ko);
    short8 b0 = *(const short8*)(bp0 + ko);
    short8 b1 = *(const short8*)(bp1 + ko);
    short8 b2 = *(const short8*)(bp2 + ko);
    short8 b3 = *(const short8*)(bp3 + ko);
    acc[0][0] = __builtin_amdgcn_mfma_f32_16x16x32_bf16(a0, b0, acc[0][0], 0, 0, 0);
    acc[0][1] = __builtin_amdgcn_mfma_f32_16x16x32_bf16(a0, b1, acc[0][1], 0, 0, 0);
    acc[0][2] = __builtin_amdgcn_mfma_f32_16x16x32_bf16(a0, b2, acc[0][2], 0, 0, 0);
    acc[0][3] = __builtin_amdgcn_mfma_f32_16x16x32_bf16(a0, b3, acc[0][3], 0, 0, 0);
    acc[1][0] = __builtin_amdgcn_mfma_f32_16x16x32_bf16(a1, b0, acc[1][0], 0, 0, 0);
    acc[1][1] = __builtin_amdgcn_mfma_f32_16x16x32_bf16(a1, b1, acc[1][1], 0, 0, 0);
    acc[1][2] = __builtin_amdgcn_mfma_f32_16x16x32_bf16(a1, b2, acc[1][2], 0, 0, 0);
    acc[1][3] = __builtin_amdgcn_mfma_f32_16x16x32_bf16(a1, b3, acc[1][3], 0, 0, 0);
  }

  // Epilogue: D layout col = lane&15, row = quad*4 + reg  [m89/m91 verified]
#pragma unroll
  for (int i = 0; i < 2; ++i) {
#pragma unroll
    for (int reg = 0; reg < 4; ++reg) {
      int grow = rowbase + i * 16 + quad * 4 + reg;
      if (grow < NN) {
#pragma unroll
        for (int j = 0; j < 4; ++j) {
          hh[(size_t)grow * FOUT + colbase + j * 16 + m] = f2bf(acc[i][j][reg]);
        }
      }
    }
  }
}

// ---------------------------------------------------------------------------
// 5) Fused SpMM + relu. One wave per output row; lane holds 2 features (bf16x2
//    gather = 4B/lane, 256B/wave/edge). Unroll-4 for MLP latency hiding.
static __device__ __forceinline__ void spmm_row(const int* __restrict__ cols,
                                                const float* __restrict__ vals,
                                                const unsigned short* __restrict__ hsrc,
                                                int s, int e, int fo,
                                                float& sx, float& sy) {
  int i = s;
  for (; i + 4 <= e; i += 4) {
    int c0 = cols[i], c1 = cols[i + 1], c2 = cols[i + 2], c3 = cols[i + 3];
    float v0 = vals[i], v1 = vals[i + 1], v2 = vals[i + 2], v3 = vals[i + 3];
    unsigned g0 = *(const unsigned*)(hsrc + c0 * FOUT + fo);
    unsigned g1 = *(const unsigned*)(hsrc + c1 * FOUT + fo);
    unsigned g2 = *(const unsigned*)(hsrc + c2 * FOUT + fo);
    unsigned g3 = *(const unsigned*)(hsrc + c3 * FOUT + fo);
    sx += v0 * __uint_as_float(g0 << 16);
    sy += v0 * __uint_as_float(g0 & 0xffff0000u);
    sx += v1 * __uint_as_float(g1 << 16);
    sy += v1 * __uint_as_float(g1 & 0xffff0000u);
    sx += v2 * __uint_as_float(g2 << 16);
    sy += v2 * __uint_as_float(g2 & 0xffff0000u);
    sx += v3 * __uint_as_float(g3 << 16);
    sy += v3 * __uint_as_float(g3 & 0xffff0000u);
  }
  for (; i < e; ++i) {
    int c = cols[i];
    float v = vals[i];
    unsigned g = *(const unsigned*)(hsrc + c * FOUT + fo);
    sx += v * __uint_as_float(g << 16);
    sy += v * __uint_as_float(g & 0xffff0000u);
  }
}

__global__ __launch_bounds__(256) void spmm_relu(
    const int* __restrict__ rp0, const int* __restrict__ cols0, const float* __restrict__ vals0,
    const int* __restrict__ rp1, const int* __restrict__ cols1, const float* __restrict__ vals1,
    const unsigned short* __restrict__ h, float* __restrict__ out) {
  const int lane = threadIdx.x & 63;
  const int wv   = threadIdx.x >> 6;
  const int r    = blockIdx.x * 4 + wv;   // 25000*4 == NN exactly
  const int fo   = lane * 2;

  const unsigned short* h0 = h;
  const unsigned short* h1 = h + (size_t)NN * FOUT;

  float sx = 0.f, sy = 0.f;
  spmm_row(cols0, vals0, h0, rp0[r], rp0[r + 1], fo, sx, sy);
  spmm_row(cols1, vals1, h1, rp1[r], rp1[r + 1], fo, sx, sy);

  f32x2 o;
  o.x = sx > 0.f ? sx : 0.f;
  o.y = sy > 0.f ? sy : 0.f;
  *(f32x2*)(out + (size_t)r * FOUT + fo) = o;
}

// ---------------------------------------------------------------------------
extern "C" void kernel_launch(void* const* d_in, const int* in_sizes, int n_in,
                              void* d_out, int out_size, void* d_ws, size_t ws_size,
                              hipStream_t stream) {
  const float* x     = (const float*)d_in[0];
  const int*   rows0 = (const int*)d_in[1];
  const int*   cols0 = (const int*)d_in[2];
  const float* vals0 = (const float*)d_in[3];
  const int*   rows1 = (const int*)d_in[4];
  const int*   cols1 = (const int*)d_in[5];
  const float* vals1 = (const float*)d_in[6];
  const float* W0    = (const float*)d_in[7];
  const float* W1    = (const float*)d_in[8];
  float* out = (float*)d_out;

  // ws layout (all 16B aligned):
  //   xb  : NN*256 bf16            = 51,200,000 B @ 0
  //   wt  : 2*128*256 bf16         =    131,072 B @ 51,200,000
  //   h   : 2*NN*128 bf16          = 51,200,000 B @ 51,331,072
  //   rp0 : (NN+1) i32 (pad 16)    =    400,016 B @ 102,531,072
  //   rp1 : (NN+1) i32             =    400,016 B @ 102,931,088
  char* ws = (char*)d_ws;
  unsigned short* xb = (unsigned short*)(ws);
  unsigned short* wt = (unsigned short*)(ws + 51200000);
  unsigned short* h  = (unsigned short*)(ws + 51331072);
  int* rp0 = (int*)(ws + 102531072);
  int* rp1 = (int*)(ws + 102931088);

  build_rowptr<<<dim3(391, 2), 256, 0, stream>>>(rows0, rows1, rp0, rp1);
  convert_x<<<25000, 256, 0, stream>>>(x, xb);
  convert_w<<<dim3(128, 2), 256, 0, stream>>>(W0, W1, wt);
  gemm_mfma<<<dim3((NN + 63) / 64, 2), 256, 0, stream>>>(xb, wt, h);
  spmm_relu<<<25000, 256, 0, stream>>>(rp0, cols0, vals0, rp1, cols1, vals1, h, out);
}

// Round 2
// 393.007 us; speedup vs baseline: 1.0599x; 1.0599x over previous
//
#include <hip/hip_runtime.h>
#include <hip/hip_bf16.h>
#include <stdint.h>

#define NN   100000
#define NE   1600000
#define KIN  256
#define FOUT 128

typedef __attribute__((ext_vector_type(8))) short short8;
typedef __attribute__((ext_vector_type(4))) float f32x4;
typedef __attribute__((ext_vector_type(2))) float f32x2;

static __device__ __forceinline__ unsigned short f2bf(float f) {
  unsigned int u = __float_as_uint(f);
  u += 0x7fffu + ((u >> 16) & 1u);   // RNE (inputs finite)
  return (unsigned short)(u >> 16);
}

static __device__ __forceinline__ short8 pack8(float4 u, float4 v) {
  short8 r;
  r[0] = (short)f2bf(u.x); r[1] = (short)f2bf(u.y);
  r[2] = (short)f2bf(u.z); r[3] = (short)f2bf(u.w);
  r[4] = (short)f2bf(v.x); r[5] = (short)f2bf(v.y);
  r[6] = (short)f2bf(v.z); r[7] = (short)f2bf(v.w);
  return r;
}

// ---------------------------------------------------------------------------
// 1) W[k][n] fp32 -> wt[which][n][k] bf16 (transposed: B-frag = 16B contig).
__global__ void convert_w(const float* __restrict__ W0, const float* __restrict__ W1,
                          unsigned short* __restrict__ wt) {
  int n = blockIdx.x;          // 0..127
  int k = threadIdx.x;         // 0..255
  int which = blockIdx.y;
  const float* W = which ? W1 : W0;
  wt[(size_t)which * (FOUT * KIN) + n * KIN + k] = f2bf(W[k * FOUT + n]);
}

// ---------------------------------------------------------------------------
// 2) rows sorted -> CSR row_ptr, linear edge scan (lower_bound semantics):
//    rp[r] = first idx with rows[idx] >= r.  Thread e covers r in
//    (rows[e], rows[e+1]]; thread 0 also covers r <= rows[0].
__global__ __launch_bounds__(256) void build_rowptr(const int* __restrict__ rows0,
                                                    const int* __restrict__ rows1,
                                                    int* __restrict__ rp0,
                                                    int* __restrict__ rp1) {
  const int e = blockIdx.x * 256 + threadIdx.x;       // 6250*256 == NE exactly
  const int* rows = blockIdx.y ? rows1 : rows0;
  int* rp = blockIdx.y ? rp1 : rp0;
  int r1 = rows[e];
  int r2 = (e + 1 < NE) ? rows[e + 1] : NN;
  if (e == 0)
    for (int r = 0; r <= r1; ++r) rp[r] = 0;
  for (int r = r1 + 1; r <= r2; ++r) rp[r] = e + 1;
}

// ---------------------------------------------------------------------------
// 3) Fused dual GEMM: h[which] = bf16( x @ W[which] ), x read as fp32 and
//    converted in-register (no xb staging pass, x read ONCE).
//    Block = 4 waves: (wv>>1) picks 32-row strip, (wv&1) picks matrix.
//    Wave tile 32 rows x 128 cols, 16x16x32 bf16 MFMA, K=256 in 8 steps.
__global__ __launch_bounds__(256) void gemm_fused(const float* __restrict__ x,
                                                  const unsigned short* __restrict__ wt,
                                                  unsigned short* __restrict__ h) {
  const int tid  = threadIdx.x;
  const int lane = tid & 63;
  const int wv   = tid >> 6;
  const int which = wv & 1;
  const int rowbase = blockIdx.x * 64 + (wv >> 1) * 32;
  const int m    = lane & 15;
  const int quad = lane >> 4;

  const unsigned short* w = wt + (size_t)which * (FOUT * KIN);
  unsigned short* hh = h + (size_t)which * NN * FOUT;

  int r0 = rowbase + m;
  int r1 = rowbase + 16 + m;
  int r0c = r0 < NN ? r0 : NN - 1;    // clamp loads; stores masked below
  int r1c = r1 < NN ? r1 : NN - 1;
  const float* ap0 = x + (size_t)r0c * KIN + quad * 8;
  const float* ap1 = x + (size_t)r1c * KIN + quad * 8;

  const unsigned short* bp[8];
#pragma unroll
  for (int j = 0; j < 8; ++j)
    bp[j] = w + (size_t)(j * 16 + m) * KIN + quad * 8;

  f32x4 acc[2][8];
#pragma unroll
  for (int i = 0; i < 2; ++i)
#pragma unroll
    for (int j = 0; j < 8; ++j)
      acc[i][j] = (f32x4){0.f, 0.f, 0.f, 0.f};

#pragma unroll
  for (int ki = 0; ki < 8; ++ki) {
    const int ko = ki * 32;           // frag covers k = ko + quad*8 .. +7
    float4 a0lo = *(const float4*)(ap0 + ko);
    float4 a0hi = *(const float4*)(ap0 + ko + 4);
    float4 a1lo = *(const float4*)(ap1 + ko);
    float4 a1hi = *(const float4*)(ap1 + ko + 4);
    short8 a0 = pack8(a0lo, a0hi);
    short8 a1 = pack8(a1lo, a1hi);
#pragma unroll
    for (int j = 0; j < 8; ++j) {
      short8 b = *(const short8*)(bp[j] + ko);
      acc[0][j] = __builtin_amdgcn_mfma_f32_16x16x32_bf16(a0, b, acc[0][j], 0, 0, 0);
      acc[1][j] = __builtin_amdgcn_mfma_f32_16x16x32_bf16(a1, b, acc[1][j], 0, 0, 0);
    }
  }

  // D layout: col = lane&15 (=m), row = quad*4 + reg  [m89/m91 verified]
#pragma unroll
  for (int i = 0; i < 2; ++i) {
#pragma unroll
    for (int reg = 0; reg < 4; ++reg) {
      int grow = rowbase + i * 16 + quad * 4 + reg;
      if (grow < NN) {
#pragma unroll
        for (int j = 0; j < 8; ++j)
          hh[(size_t)grow * FOUT + j * 16 + m] = f2bf(acc[i][j][reg]);
      }
    }
  }
}

// ---------------------------------------------------------------------------
// 4) Fused SpMM + relu. One wave per row; lane holds 2 features (4B gather,
//    full 256B h-row per edge). Edge metadata forced wave-uniform (scalar
//    s_load batches), unroll 8 for MLP; nontemporal output store so the 51MB
//    output doesn't evict h from L2/L3.
static __device__ __forceinline__ void spmm_row(const int* __restrict__ cols,
                                                const float* __restrict__ vals,
                                                const unsigned short* __restrict__ hsrc,
                                                const int* __restrict__ rp,
                                                int r, int fo,
                                                float& sx, float& sy) {
  int s = __builtin_amdgcn_readfirstlane(rp[r]);
  int e = __builtin_amdgcn_readfirstlane(rp[r + 1]);
  int i = s;
  for (; i + 8 <= e; i += 8) {
    unsigned g[8];
#pragma unroll
    for (int u = 0; u < 8; ++u) {
      int c = cols[i + u];                       // uniform -> s_load_dwordx4
      g[u] = *(const unsigned*)(hsrc + (size_t)c * FOUT + fo);
    }
#pragma unroll
    for (int u = 0; u < 8; ++u) {
      float v = vals[i + u];                     // uniform -> s_load
      sx += v * __uint_as_float(g[u] << 16);
      sy += v * __uint_as_float(g[u] & 0xffff0000u);
    }
  }
  for (; i < e; ++i) {
    int c = cols[i];
    float v = vals[i];
    unsigned g = *(const unsigned*)(hsrc + (size_t)c * FOUT + fo);
    sx += v * __uint_as_float(g << 16);
    sy += v * __uint_as_float(g & 0xffff0000u);
  }
}

__global__ __launch_bounds__(256) void spmm_relu(
    const int* __restrict__ rp0, const int* __restrict__ cols0, const float* __restrict__ vals0,
    const int* __restrict__ rp1, const int* __restrict__ cols1, const float* __restrict__ vals1,
    const unsigned short* __restrict__ h, float* __restrict__ out) {
  const int lane = threadIdx.x & 63;
  int r = blockIdx.x * 4 + (threadIdx.x >> 6);   // 25000*4 == NN exactly
  r = __builtin_amdgcn_readfirstlane(r);
  const int fo = lane * 2;

  const unsigned short* h0 = h;
  const unsigned short* h1 = h + (size_t)NN * FOUT;

  float sx = 0.f, sy = 0.f;
  spmm_row(cols0, vals0, h0, rp0, r, fo, sx, sy);
  spmm_row(cols1, vals1, h1, rp1, r, fo, sx, sy);

  f32x2 o;
  o.x = sx > 0.f ? sx : 0.f;
  o.y = sy > 0.f ? sy : 0.f;
  __builtin_nontemporal_store(o, (f32x2*)(out + (size_t)r * FOUT + fo));
}

// ---------------------------------------------------------------------------
extern "C" void kernel_launch(void* const* d_in, const int* in_sizes, int n_in,
                              void* d_out, int out_size, void* d_ws, size_t ws_size,
                              hipStream_t stream) {
  const float* x     = (const float*)d_in[0];
  const int*   rows0 = (const int*)d_in[1];
  const int*   cols0 = (const int*)d_in[2];
  const float* vals0 = (const float*)d_in[3];
  const int*   rows1 = (const int*)d_in[4];
  const int*   cols1 = (const int*)d_in[5];
  const float* vals1 = (const float*)d_in[6];
  const float* W0    = (const float*)d_in[7];
  const float* W1    = (const float*)d_in[8];
  float* out = (float*)d_out;

  // ws layout (16B aligned):
  //   wt  : 2*128*256 bf16 =    131,072 B @ 0
  //   h   : 2*NN*128 bf16  = 51,200,000 B @ 131,072
  //   rp0 : (NN+1) i32     (padded to 400,064) @ 51,331,072
  //   rp1 : (NN+1) i32     @ 51,731,136
  char* ws = (char*)d_ws;
  unsigned short* wt = (unsigned short*)(ws);
  unsigned short* h  = (unsigned short*)(ws + 131072);
  int* rp0 = (int*)(ws + 51331072);
  int* rp1 = (int*)(ws + 51731136);

  build_rowptr<<<dim3(6250, 2), 256, 0, stream>>>(rows0, rows1, rp0, rp1);
  convert_w<<<dim3(128, 2), 256, 0, stream>>>(W0, W1, wt);
  gemm_fused<<<(NN + 63) / 64, 256, 0, stream>>>(x, wt, h);
  spmm_relu<<<25000, 256, 0, stream>>>(rp0, cols0, vals0, rp1, cols1, vals1, h, out);
}

// Round 3
// 386.184 us; speedup vs baseline: 1.0786x; 1.0177x over previous
//
#include <hip/hip_runtime.h>
#include <hip/hip_bf16.h>
#include <stdint.h>

#define NN   100000
#define NE   1600000
#define KIN  256
#define FOUT 128

typedef __attribute__((ext_vector_type(8))) short short8;
typedef __attribute__((ext_vector_type(4))) float f32x4;
typedef __attribute__((ext_vector_type(2))) float f32x2;

static __device__ __forceinline__ unsigned short f2bf(float f) {
  unsigned int u = __float_as_uint(f);
  u += 0x7fffu + ((u >> 16) & 1u);   // RNE (inputs finite)
  return (unsigned short)(u >> 16);
}

static __device__ __forceinline__ short8 pack8(float4 u, float4 v) {
  short8 r;
  r[0] = (short)f2bf(u.x); r[1] = (short)f2bf(u.y);
  r[2] = (short)f2bf(u.z); r[3] = (short)f2bf(u.w);
  r[4] = (short)f2bf(v.x); r[5] = (short)f2bf(v.y);
  r[6] = (short)f2bf(v.z); r[7] = (short)f2bf(v.w);
  return r;
}

// ---------------------------------------------------------------------------
// 1) W[k][n] fp32 -> wt[which][n][k] bf16 (transposed: B-frag = 16B contig).
__global__ void convert_w(const float* __restrict__ W0, const float* __restrict__ W1,
                          unsigned short* __restrict__ wt) {
  int n = blockIdx.x;          // 0..127
  int k = threadIdx.x;         // 0..255
  int which = blockIdx.y;
  const float* W = which ? W1 : W0;
  wt[(size_t)which * (FOUT * KIN) + n * KIN + k] = f2bf(W[k * FOUT + n]);
}

// ---------------------------------------------------------------------------
// 2) rows sorted -> CSR row_ptr, linear edge scan (lower_bound semantics).
__global__ __launch_bounds__(256) void build_rowptr(const int* __restrict__ rows0,
                                                    const int* __restrict__ rows1,
                                                    int* __restrict__ rp0,
                                                    int* __restrict__ rp1) {
  const int e = blockIdx.x * 256 + threadIdx.x;       // 6250*256 == NE exactly
  const int* rows = blockIdx.y ? rows1 : rows0;
  int* rp = blockIdx.y ? rp1 : rp0;
  int r1 = rows[e];
  int r2 = (e + 1 < NE) ? rows[e + 1] : NN;
  if (e == 0)
    for (int r = 0; r <= r1; ++r) rp[r] = 0;
  for (int r = r1 + 1; r <= r2; ++r) rp[r] = e + 1;
}

// ---------------------------------------------------------------------------
// 3) GEMM h[which] = bf16( x @ W[which] ), x fp32 read + in-register convert.
//    grid (1563, 2): blockIdx.y = which. Block 4 waves, tile 64x128.
//    Wave tile 32 rows x 64 cols: acc[2][4] = 32 VGPR. K-loop unroll 2 to cap
//    register pressure (R2's full unroll suspected of scratch spill).
//    Epilogue: wave-private LDS stage -> coalesced 16B global stores.
__global__ __launch_bounds__(256) void gemm_mfma(const float* __restrict__ x,
                                                 const unsigned short* __restrict__ wt,
                                                 unsigned short* __restrict__ h) {
  __shared__ __align__(16) unsigned short tile[4][32 * 64];   // 16 KB

  const int tid  = threadIdx.x;
  const int lane = tid & 63;
  const int wv   = tid >> 6;
  const int which = blockIdx.y;
  const int rowbase = blockIdx.x * 64 + (wv >> 1) * 32;
  const int colbase = (wv & 1) * 64;
  const int m    = lane & 15;
  const int quad = lane >> 4;

  const unsigned short* w = wt + (size_t)which * (FOUT * KIN);
  unsigned short* hh = h + (size_t)which * NN * FOUT;

  int r0 = rowbase + m;
  int r1 = rowbase + 16 + m;
  int r0c = r0 < NN ? r0 : NN - 1;    // clamp loads; stores masked below
  int r1c = r1 < NN ? r1 : NN - 1;
  const float* ap0 = x + (size_t)r0c * KIN + quad * 8;
  const float* ap1 = x + (size_t)r1c * KIN + quad * 8;
  const unsigned short* b0p = w + (size_t)(colbase + 0  + m) * KIN + quad * 8;
  const unsigned short* b1p = w + (size_t)(colbase + 16 + m) * KIN + quad * 8;
  const unsigned short* b2p = w + (size_t)(colbase + 32 + m) * KIN + quad * 8;
  const unsigned short* b3p = w + (size_t)(colbase + 48 + m) * KIN + quad * 8;

  f32x4 acc[2][4];
#pragma unroll
  for (int i = 0; i < 2; ++i)
#pragma unroll
    for (int j = 0; j < 4; ++j)
      acc[i][j] = (f32x4){0.f, 0.f, 0.f, 0.f};

#pragma unroll 2
  for (int ko = 0; ko < KIN; ko += 32) {
    float4 a0lo = *(const float4*)(ap0 + ko);
    float4 a0hi = *(const float4*)(ap0 + ko + 4);
    float4 a1lo = *(const float4*)(ap1 + ko);
    float4 a1hi = *(const float4*)(ap1 + ko + 4);
    short8 b0 = *(const short8*)(b0p + ko);
    short8 b1 = *(const short8*)(b1p + ko);
    short8 b2 = *(const short8*)(b2p + ko);
    short8 b3 = *(const short8*)(b3p + ko);
    short8 a0 = pack8(a0lo, a0hi);
    short8 a1 = pack8(a1lo, a1hi);
    acc[0][0] = __builtin_amdgcn_mfma_f32_16x16x32_bf16(a0, b0, acc[0][0], 0, 0, 0);
    acc[0][1] = __builtin_amdgcn_mfma_f32_16x16x32_bf16(a0, b1, acc[0][1], 0, 0, 0);
    acc[0][2] = __builtin_amdgcn_mfma_f32_16x16x32_bf16(a0, b2, acc[0][2], 0, 0, 0);
    acc[0][3] = __builtin_amdgcn_mfma_f32_16x16x32_bf16(a0, b3, acc[0][3], 0, 0, 0);
    acc[1][0] = __builtin_amdgcn_mfma_f32_16x16x32_bf16(a1, b0, acc[1][0], 0, 0, 0);
    acc[1][1] = __builtin_amdgcn_mfma_f32_16x16x32_bf16(a1, b1, acc[1][1], 0, 0, 0);
    acc[1][2] = __builtin_amdgcn_mfma_f32_16x16x32_bf16(a1, b2, acc[1][2], 0, 0, 0);
    acc[1][3] = __builtin_amdgcn_mfma_f32_16x16x32_bf16(a1, b3, acc[1][3], 0, 0, 0);
  }

  // Stage wave's 32x64 bf16 tile in wave-private LDS (no barrier needed:
  // same-wave LDS RAW, compiler inserts lgkmcnt).
  // D layout: col = lane&15 (=m), row = quad*4 + reg  [m89/m91 verified]
#pragma unroll
  for (int i = 0; i < 2; ++i)
#pragma unroll
    for (int reg = 0; reg < 4; ++reg)
#pragma unroll
      for (int j = 0; j < 4; ++j)
        tile[wv][(i * 16 + quad * 4 + reg) * 64 + j * 16 + m] = f2bf(acc[i][j][reg]);

  // Read back coalesced: 4 passes x (64 lanes x 16B) = 4 KB.
#pragma unroll
  for (int p = 0; p < 4; ++p) {
    int row = p * 8 + (lane >> 3);        // 0..31
    int colb = (lane & 7) * 8;            // element offset within 64-col strip
    uint4 v = *(const uint4*)&tile[wv][row * 64 + colb];
    int grow = rowbase + row;
    if (grow < NN)
      *(uint4*)&hh[(size_t)grow * FOUT + colbase + colb] = v;
  }
}

// ---------------------------------------------------------------------------
// 4) Fused SpMM + relu. One wave per row; lane = 2 features (256B/edge
//    coalesced gather). Main loop issues 8 gathers for BOTH matrices (16
//    outstanding) before consuming either; unroll-4 tails. Edge metadata
//    scalarized (rp via readfirstlane -> s_load batches). NT output store.
static __device__ __forceinline__ void consume8(const float* __restrict__ vals, int i,
                                                const unsigned* g, float& sx, float& sy) {
#pragma unroll
  for (int u = 0; u < 8; ++u) {
    float v = vals[i + u];
    sx += v * __uint_as_float(g[u] << 16);
    sy += v * __uint_as_float(g[u] & 0xffff0000u);
  }
}

static __device__ __forceinline__ void tail_spmm(const int* __restrict__ cols,
                                                 const float* __restrict__ vals,
                                                 const unsigned short* __restrict__ hsrc,
                                                 int i, int e, int fo,
                                                 float& sx, float& sy) {
  for (; i + 4 <= e; i += 4) {
    int c0 = cols[i], c1 = cols[i + 1], c2 = cols[i + 2], c3 = cols[i + 3];
    unsigned g0 = *(const unsigned*)(hsrc + (size_t)c0 * FOUT + fo);
    unsigned g1 = *(const unsigned*)(hsrc + (size_t)c1 * FOUT + fo);
    unsigned g2 = *(const unsigned*)(hsrc + (size_t)c2 * FOUT + fo);
    unsigned g3 = *(const unsigned*)(hsrc + (size_t)c3 * FOUT + fo);
    float v0 = vals[i], v1 = vals[i + 1], v2 = vals[i + 2], v3 = vals[i + 3];
    sx += v0 * __uint_as_float(g0 << 16);
    sy += v0 * __uint_as_float(g0 & 0xffff0000u);
    sx += v1 * __uint_as_float(g1 << 16);
    sy += v1 * __uint_as_float(g1 & 0xffff0000u);
    sx += v2 * __uint_as_float(g2 << 16);
    sy += v2 * __uint_as_float(g2 & 0xffff0000u);
    sx += v3 * __uint_as_float(g3 << 16);
    sy += v3 * __uint_as_float(g3 & 0xffff0000u);
  }
  for (; i < e; ++i) {
    int c = cols[i];
    float v = vals[i];
    unsigned g = *(const unsigned*)(hsrc + (size_t)c * FOUT + fo);
    sx += v * __uint_as_float(g << 16);
    sy += v * __uint_as_float(g & 0xffff0000u);
  }
}

__global__ __launch_bounds__(256) void spmm_relu(
    const int* __restrict__ rp0, const int* __restrict__ cols0, const float* __restrict__ vals0,
    const int* __restrict__ rp1, const int* __restrict__ cols1, const float* __restrict__ vals1,
    const unsigned short* __restrict__ h, float* __restrict__ out) {
  const int lane = threadIdx.x & 63;
  int r = blockIdx.x * 4 + (threadIdx.x >> 6);   // 25000*4 == NN exactly
  r = __builtin_amdgcn_readfirstlane(r);
  const int fo = lane * 2;

  const unsigned short* h0 = h;
  const unsigned short* h1 = h + (size_t)NN * FOUT;

  int i0 = __builtin_amdgcn_readfirstlane(rp0[r]);
  int e0 = __builtin_amdgcn_readfirstlane(rp0[r + 1]);
  int i1 = __builtin_amdgcn_readfirstlane(rp1[r]);
  int e1 = __builtin_amdgcn_readfirstlane(rp1[r + 1]);

  float sx = 0.f, sy = 0.f;

  // Main: dual-matrix batches, 16 gathers in flight.
  while (i0 + 8 <= e0 && i1 + 8 <= e1) {
    unsigned g0[8], g1[8];
#pragma unroll
    for (int u = 0; u < 8; ++u) {
      int c = cols0[i0 + u];                     // uniform -> s_load
      g0[u] = *(const unsigned*)(h0 + (size_t)c * FOUT + fo);
    }
#pragma unroll
    for (int u = 0; u < 8; ++u) {
      int c = cols1[i1 + u];
      g1[u] = *(const unsigned*)(h1 + (size_t)c * FOUT + fo);
    }
    consume8(vals0, i0, g0, sx, sy);
    consume8(vals1, i1, g1, sx, sy);
    i0 += 8;
    i1 += 8;
  }
  tail_spmm(cols0, vals0, h0, i0, e0, fo, sx, sy);
  tail_spmm(cols1, vals1, h1, i1, e1, fo, sx, sy);

  f32x2 o;
  o.x = sx > 0.f ? sx : 0.f;
  o.y = sy > 0.f ? sy : 0.f;
  __builtin_nontemporal_store(o, (f32x2*)(out + (size_t)r * FOUT + fo));
}

// ---------------------------------------------------------------------------
extern "C" void kernel_launch(void* const* d_in, const int* in_sizes, int n_in,
                              void* d_out, int out_size, void* d_ws, size_t ws_size,
                              hipStream_t stream) {
  const float* x     = (const float*)d_in[0];
  const int*   rows0 = (const int*)d_in[1];
  const int*   cols0 = (const int*)d_in[2];
  const float* vals0 = (const float*)d_in[3];
  const int*   rows1 = (const int*)d_in[4];
  const int*   cols1 = (const int*)d_in[5];
  const float* vals1 = (const float*)d_in[6];
  const float* W0    = (const float*)d_in[7];
  const float* W1    = (const float*)d_in[8];
  float* out = (float*)d_out;

  // ws layout (16B aligned):
  //   wt  : 2*128*256 bf16 =    131,072 B @ 0
  //   h   : 2*NN*128 bf16  = 51,200,000 B @ 131,072
  //   rp0 : (NN+1) i32     @ 51,331,072
  //   rp1 : (NN+1) i32     @ 51,731,136
  char* ws = (char*)d_ws;
  unsigned short* wt = (unsigned short*)(ws);
  unsigned short* h  = (unsigned short*)(ws + 131072);
  int* rp0 = (int*)(ws + 51331072);
  int* rp1 = (int*)(ws + 51731136);

  build_rowptr<<<dim3(6250, 2), 256, 0, stream>>>(rows0, rows1, rp0, rp1);
  convert_w<<<dim3(128, 2), 256, 0, stream>>>(W0, W1, wt);
  gemm_mfma<<<dim3((NN + 63) / 64, 2), 256, 0, stream>>>(x, wt, h);
  spmm_relu<<<25000, 256, 0, stream>>>(rp0, cols0, vals0, rp1, cols1, vals1, h, out);
}